// Round 17
// baseline (193.788 us; speedup 1.0000x reference)
//
#include <hip/hip_runtime.h>
#include <hip/hip_bf16.h>
#include <math.h>

// Problem constants
#define TT 16
#define NROI 32
#define BB 16
#define HID 768
#define NODES 512            // per graph
#define MROWS (BB * NODES)   // 8192
#define D1 512               // H=4, C=128
#define D2 128               // H=1, C=128

typedef __attribute__((ext_vector_type(8))) short short8;
typedef __attribute__((ext_vector_type(4))) float f32x4;

__device__ __forceinline__ void bf16_split(float v, short& h, short& l) {
    unsigned u = __float_as_uint(v);
    h = (short)(u >> 16);
    float r = v - __uint_as_float(u & 0xFFFF0000u);
    l = (short)(__float_as_uint(r) >> 16);
}

// round-to-nearest-even bf16 (unbiased; errors sqrt-N cancel in long sums)
__device__ __forceinline__ short bf16_rne(float v) {
    unsigned u = __float_as_uint(v);
    unsigned r = u + 0x7FFF + ((u >> 16) & 1);
    return (short)(r >> 16);
}
__device__ __forceinline__ float bf16_f32(short s) {
    return __uint_as_float(((unsigned)(unsigned short)s) << 16);
}

__device__ __forceinline__ float lrelu02(float v) { return v > 0.0f ? v : 0.2f * v; }

// ---------------------------------------------------------------------------
// prep_kernel: W1/W2 transpose+split (112 blocks) + classifier fuse + counter
// zero (1 block).
// ---------------------------------------------------------------------------
__launch_bounds__(256)
__global__ void prep_kernel(const float* __restrict__ W1, short* __restrict__ w1h,
                            short* __restrict__ w1l, const float* __restrict__ W2,
                            short* __restrict__ w2h, short* __restrict__ w2l,
                            const float* __restrict__ fc_w, const float* __restrict__ fc_b,
                            const float* __restrict__ cls_w, const float* __restrict__ cls_b,
                            float* __restrict__ fw, float* __restrict__ fb,
                            int* __restrict__ done_ctr) {
    const int bid = blockIdx.x;
    const int tid = threadIdx.x;

    if (bid < 112) {
        __shared__ unsigned tile[64][65];
        const float* W; short *hi, *lo; int K, N, k0, n0;
        if (bid < 96) {
            W = W1; hi = w1h; lo = w1l; K = HID; N = D1;
            k0 = (bid >> 3) * 64; n0 = (bid & 7) * 64;
        } else {
            int idx = bid - 96;
            W = W2; hi = w2h; lo = w2l; K = D1; N = D2;
            k0 = (idx >> 1) * 64; n0 = (idx & 1) * 64;
        }
#pragma unroll
        for (int it = 0; it < 16; ++it) {
            int i = it * 256 + tid;
            int r = i >> 6, j = i & 63;
            float v = W[(size_t)(k0 + r) * N + n0 + j];
            short h, l;
            bf16_split(v, h, l);
            tile[r][j] = ((unsigned)(unsigned short)h << 16) | (unsigned)(unsigned short)l;
        }
        __syncthreads();
#pragma unroll
        for (int it = 0; it < 16; ++it) {
            int i = it * 256 + tid;
            int rr = i >> 6, c = i & 63;
            unsigned p = tile[c][rr];
            hi[(size_t)(n0 + rr) * K + k0 + c] = (short)(p >> 16);
            lo[(size_t)(n0 + rr) * K + k0 + c] = (short)(p & 0xFFFF);
        }
        return;
    }

    // ---- fuse_cls + counter zero ----
    if (tid == 0) *done_ctr = 0;
    const int t = tid;
    const int c = t >> 1, j = t & 1;
    const float* wr = fc_w + (size_t)c * HID;
    float s = 0.0f;
#pragma unroll 4
    for (int o = 0; o < HID; o += 4) {
        float4 w4 = *(const float4*)(wr + o);
        s += w4.x * cls_w[(o + 0) * 2 + j] + w4.y * cls_w[(o + 1) * 2 + j]
           + w4.z * cls_w[(o + 2) * 2 + j] + w4.w * cls_w[(o + 3) * 2 + j];
    }
    fw[c * 2 + j] = s;

    __shared__ float p0[256], p1[256];
    float a0 = 0.0f, a1 = 0.0f;
    for (int o = t * 3; o < t * 3 + 3; ++o) {
        float v = fc_b[o];
        a0 += v * cls_w[o * 2 + 0];
        a1 += v * cls_w[o * 2 + 1];
    }
    p0[t] = a0; p1[t] = a1;
    __syncthreads();
    for (int off = 128; off > 0; off >>= 1) {
        if (t < off) { p0[t] += p0[t + off]; p1[t] += p1[t + off]; }
        __syncthreads();
    }
    if (t == 0) { fb[0] = p0[0] + cls_b[0]; fb[1] = p1[0] + cls_b[1]; }
}

// ---------------------------------------------------------------------------
// bf16 MFMA GEMM, 2-term (A single bf16; B split hi/lo).  Round-13 structure:
// 256 threads, BM=64, BN=128, BK=32, depth-1 reg-staged double buffer.
// AFP32: A source fp32, RNE-converted in-register during staging.
// CBF16: C stored as RNE bf16.
// PROJ=4: block owns head hh=blockIdx.x -> as_o[row*4+hh]; PROJ=1: as_o[row].
// ---------------------------------------------------------------------------
template <int PROJ, bool AFP32, bool CBF16>
__launch_bounds__(256)
__global__ void gemm_ps_kernel(const void* __restrict__ Av,
                               const short* __restrict__ Bh, const short* __restrict__ Bl,
                               void* __restrict__ Cv,
                               const float* __restrict__ asw, const float* __restrict__ adw,
                               float* __restrict__ as_o, float* __restrict__ ad_o,
                               int N, int K) {
    constexpr int BM = 64, BN = 128, BK = 32, LD = BK + 8;
    __shared__ __align__(16) short As[2][BM][LD];
    __shared__ __align__(16) short Bs[2][2][BN][LD];
    __shared__ float eps[2][BM], epd[2][BM];

    const int tid = threadIdx.x, lane = tid & 63, wid = tid >> 6;
    const int brow = blockIdx.y * BM, bcol = blockIdx.x * BN;
    const int wm = (wid >> 1) * 32, wn = (wid & 1) * 64;
    const int frow = lane & 15, fk = (lane >> 4) * 8;

    f32x4 acc[2][4];
#pragma unroll
    for (int m = 0; m < 2; ++m)
#pragma unroll
        for (int n = 0; n < 4; ++n) acc[m][n] = (f32x4)0.0f;

    short8 a_h, b_h[2], b_l[2];
    const int arow = tid >> 2, ag = tid & 3;

    auto load_tiles = [&](int k0) {
        const size_t aoff = (size_t)(brow + arow) * K + k0 + ag * 8;
        if constexpr (AFP32) {
            const float* Af = (const float*)Av;
            float4 v0 = *(const float4*)(Af + aoff);
            float4 v1 = *(const float4*)(Af + aoff + 4);
            a_h[0] = bf16_rne(v0.x); a_h[1] = bf16_rne(v0.y);
            a_h[2] = bf16_rne(v0.z); a_h[3] = bf16_rne(v0.w);
            a_h[4] = bf16_rne(v1.x); a_h[5] = bf16_rne(v1.y);
            a_h[6] = bf16_rne(v1.z); a_h[7] = bf16_rne(v1.w);
        } else {
            a_h = *(const short8*)((const short*)Av + aoff);
        }
#pragma unroll
        for (int it = 0; it < 2; ++it) {
            int idx = it * 256 + tid;
            int row = idx >> 2, g = idx & 3;
            const size_t boff = (size_t)(bcol + row) * K + k0 + g * 8;
            b_h[it] = *(const short8*)(Bh + boff);
            b_l[it] = *(const short8*)(Bl + boff);
        }
    };
    auto write_tiles = [&](int buf) {
        *(short8*)&As[buf][arow][ag * 8] = a_h;
#pragma unroll
        for (int it = 0; it < 2; ++it) {
            int idx = it * 256 + tid;
            int row = idx >> 2, g = idx & 3;
            *(short8*)&Bs[buf][0][row][g * 8] = b_h[it];
            *(short8*)&Bs[buf][1][row][g * 8] = b_l[it];
        }
    };

    const int NT = K / BK;
    load_tiles(0);
    write_tiles(0);
    __syncthreads();
    int cur = 0;
    for (int t = 0; t < NT; ++t) {
        if (t + 1 < NT) load_tiles((t + 1) * BK);

        short8 ah[2], bhf[4], blf[4];
#pragma unroll
        for (int m = 0; m < 2; ++m)
            ah[m] = *(const short8*)&As[cur][wm + m * 16 + frow][fk];
#pragma unroll
        for (int n = 0; n < 4; ++n) {
            bhf[n] = *(const short8*)&Bs[cur][0][wn + n * 16 + frow][fk];
            blf[n] = *(const short8*)&Bs[cur][1][wn + n * 16 + frow][fk];
        }
#pragma unroll
        for (int m = 0; m < 2; ++m)
#pragma unroll
            for (int n = 0; n < 4; ++n) {
                acc[m][n] = __builtin_amdgcn_mfma_f32_16x16x32_bf16(ah[m], bhf[n], acc[m][n], 0, 0, 0);
                acc[m][n] = __builtin_amdgcn_mfma_f32_16x16x32_bf16(ah[m], blf[n], acc[m][n], 0, 0, 0);
            }

        if (t + 1 < NT) write_tiles(cur ^ 1);
        __syncthreads();
        cur ^= 1;
    }

    // C write: D[row=(lane>>4)*4+j][col=lane&15]
#pragma unroll
    for (int m = 0; m < 2; ++m)
#pragma unroll
        for (int n = 0; n < 4; ++n) {
            const int col = bcol + wn + n * 16 + (lane & 15);
            const int r0 = brow + wm + m * 16 + (lane >> 4) * 4;
#pragma unroll
            for (int j = 0; j < 4; ++j) {
                if constexpr (CBF16)
                    ((short*)Cv)[(size_t)(r0 + j) * N + col] = bf16_rne(acc[m][n][j]);
                else
                    ((float*)Cv)[(size_t)(r0 + j) * N + col] = acc[m][n][j];
            }
        }

    if constexpr (PROJ > 0) {
        const int hh = (PROJ == 4) ? (int)blockIdx.x : 0;
        float aw[4], dw[4];
#pragma unroll
        for (int n = 0; n < 4; ++n) {
            int c = wn + n * 16 + (lane & 15);
            aw[n] = asw[hh * 128 + c];
            dw[n] = adw[hh * 128 + c];
        }
        float ps[2][4], pd[2][4];
#pragma unroll
        for (int m = 0; m < 2; ++m)
#pragma unroll
            for (int j = 0; j < 4; ++j) {
                float s = 0.0f, d = 0.0f;
#pragma unroll
                for (int n = 0; n < 4; ++n) {
                    s += acc[m][n][j] * aw[n];
                    d += acc[m][n][j] * dw[n];
                }
                ps[m][j] = s; pd[m][j] = d;
            }
#pragma unroll
        for (int off = 1; off < 16; off <<= 1)
#pragma unroll
            for (int m = 0; m < 2; ++m)
#pragma unroll
                for (int j = 0; j < 4; ++j) {
                    ps[m][j] += __shfl_xor(ps[m][j], off);
                    pd[m][j] += __shfl_xor(pd[m][j], off);
                }
        if ((lane & 15) == 0) {
#pragma unroll
            for (int m = 0; m < 2; ++m)
#pragma unroll
                for (int j = 0; j < 4; ++j) {
                    int rl = wm + m * 16 + (lane >> 4) * 4 + j;
                    eps[wid & 1][rl] = ps[m][j];
                    epd[wid & 1][rl] = pd[m][j];
                }
        }
        __syncthreads();
        if (tid < BM) {
            float s = eps[0][tid] + eps[1][tid];
            float d = epd[0][tid] + epd[1][tid];
            if (PROJ == 4) {
                as_o[(size_t)(brow + tid) * 4 + hh] = s;
                ad_o[(size_t)(brow + tid) * 4 + hh] = d;
            } else {
                as_o[brow + tid] = s;
                ad_o[brow + tid] = d;
            }
        }
    }
}

// ---------------------------------------------------------------------------
// Wave-parallel per-row softmax into sal[NROI][36].
// ---------------------------------------------------------------------------
__device__ __forceinline__ void softmax_rows(const float* sas, const float* sad,
                                             const float* sasm, const float* sasp,
                                             float (*sal)[36], int t, int tid) {
    if (tid < 128) {
        const int r = tid >> 2, p = tid & 3;
        const float ad = sad[r];
        float e[8];
        float m = -1e30f;
#pragma unroll
        for (int k = 0; k < 8; ++k) {
            e[k] = lrelu02(sas[p * 8 + k] + ad);
            m = fmaxf(m, e[k]);
        }
        m = fmaxf(m, __shfl_xor(m, 1));
        m = fmaxf(m, __shfl_xor(m, 2));
        const bool hp = (t > 0), hn = (t < TT - 1);
        float vp = 0.0f, vn = 0.0f;
        if (hp) { vp = lrelu02(sasm[r] + ad); m = fmaxf(m, vp); }
        if (hn) { vn = lrelu02(sasp[r] + ad); m = fmaxf(m, vn); }
        float sum = 0.0f;
#pragma unroll
        for (int k = 0; k < 8; ++k) {
            float x = expf(e[k] - m);
            e[k] = x;
            sum += x;
        }
        sum += __shfl_xor(sum, 1);
        sum += __shfl_xor(sum, 2);
        float ep = hp ? expf(vp - m) : 0.0f;
        float en = hn ? expf(vn - m) : 0.0f;
        sum += ep + en;
        float inv = 1.0f / (sum + 1e-16f);
#pragma unroll
        for (int k = 0; k < 8; ++k) sal[r][p * 8 + k] = e[k] * inv;
        if (p == 0) { sal[r][32] = ep * inv; sal[r][33] = en * inv; }
    }
}

// ---------------------------------------------------------------------------
// GAT layer-1 edge agg, per-head blocks, register-blocked, bf16 h1 input,
// single-RNE-bf16 x1 output (stride-4 a_s/a_d).
// ---------------------------------------------------------------------------
__launch_bounds__(256)
__global__ void edge_agg1_kernel(const short* __restrict__ h1b, const float* __restrict__ a_s,
                                 const float* __restrict__ a_d, const float* __restrict__ b1,
                                 short* __restrict__ x1b) {
    const int bid = blockIdx.x;
    const int hh = bid & 3;
    const int bt = bid >> 2;
    const int b = bt >> 4;
    const int t = bt & 15;
    const int tid = threadIdx.x;
    __shared__ float sh[NROI * 128];     // 16 KB (fp32, converted at stage)
    __shared__ float sal[NROI][36];
    __shared__ float sas[NROI], sad[NROI], sasm[NROI], sasp[NROI];

    const int base = b * NODES + t * NROI;
    const short* src = h1b + (size_t)base * D1 + hh * 128;
#pragma unroll
    for (int it = 0; it < 2; ++it) {
        int i = it * 256 + tid;
        int row = i >> 4, c8 = (i & 15) * 8;
        short8 v = *(const short8*)&src[(size_t)row * D1 + c8];
        float* dst = &sh[row * 128 + c8];
#pragma unroll
        for (int j = 0; j < 8; ++j) dst[j] = bf16_f32(v[j]);
    }
    if (tid < NROI) {
        sas[tid] = a_s[(base + tid) * 4 + hh];
        sad[tid] = a_d[(base + tid) * 4 + hh];
        sasm[tid] = (t > 0) ? a_s[(base - NROI + tid) * 4 + hh] : 0.0f;
        sasp[tid] = (t < TT - 1) ? a_s[(base + NROI + tid) * 4 + hh] : 0.0f;
    }
    __syncthreads();

    softmax_rows(sas, sad, sasm, sasp, sal, t, tid);
    __syncthreads();

    const short* hprev = h1b + (size_t)(base - NROI) * D1 + hh * 128;
    const short* hnext = h1b + (size_t)(base + NROI) * D1 + hh * 128;
    short* outp = x1b + (size_t)base * D1 + hh * 128;

    const int g = tid >> 5;              // row group 0..7
    const int ch0 = (tid & 31) * 4;      // channel within slice
    const float4 bb = *(const float4*)&b1[hh * 128 + ch0];

    f32x4 acc[4];
#pragma unroll
    for (int rr = 0; rr < 4; ++rr) acc[rr] = (f32x4)0.0f;

#pragma unroll
    for (int sb = 0; sb < NROI; sb += 4) {
        f32x4 a0 = *(const f32x4*)&sal[g][sb];
        f32x4 a1 = *(const f32x4*)&sal[g + 8][sb];
        f32x4 a2 = *(const f32x4*)&sal[g + 16][sb];
        f32x4 a3 = *(const f32x4*)&sal[g + 24][sb];
#pragma unroll
        for (int k = 0; k < 4; ++k) {
            f32x4 v = *(const f32x4*)&sh[(sb + k) * 128 + ch0];
            acc[0] += a0[k] * v;
            acc[1] += a1[k] * v;
            acc[2] += a2[k] * v;
            acc[3] += a3[k] * v;
        }
    }

#pragma unroll
    for (int rr = 0; rr < 4; ++rr) {
        const int r = g + rr * 8;
        f32x4 a = acc[rr];
        if (t > 0) {
            short4 v4 = *(const short4*)&hprev[(size_t)r * D1 + ch0];
            float w = sal[r][32];
            a[0] += w * bf16_f32(v4.x); a[1] += w * bf16_f32(v4.y);
            a[2] += w * bf16_f32(v4.z); a[3] += w * bf16_f32(v4.w);
        }
        if (t < TT - 1) {
            short4 v4 = *(const short4*)&hnext[(size_t)r * D1 + ch0];
            float w = sal[r][33];
            a[0] += w * bf16_f32(v4.x); a[1] += w * bf16_f32(v4.y);
            a[2] += w * bf16_f32(v4.z); a[3] += w * bf16_f32(v4.w);
        }
        a[0] += bb.x; a[1] += bb.y; a[2] += bb.z; a[3] += bb.w;
#pragma unroll
        for (int k = 0; k < 4; ++k) a[k] = a[k] > 0.f ? a[k] : expf(a[k]) - 1.f;
        short4 o;
        o.x = bf16_rne(a[0]); o.y = bf16_rne(a[1]);
        o.z = bf16_rne(a[2]); o.w = bf16_rne(a[3]);
        *(short4*)&outp[(size_t)r * D1 + ch0] = o;
    }
}

// ---------------------------------------------------------------------------
// GAT layer-2 edge agg + pool partials, per-quarter blocks.  The LAST block
// (device atomic counter) also performs the frame-sum + collapsed classifier
// (pool_cls fused; one launch saved).
// ---------------------------------------------------------------------------
__launch_bounds__(256)
__global__ void edge_agg2_pool_kernel(const float* __restrict__ h2, const float* __restrict__ a_s,
                                      const float* __restrict__ a_d, const float* __restrict__ b2,
                                      float* __restrict__ pg, const float* __restrict__ fw,
                                      const float* __restrict__ fb, float* __restrict__ out,
                                      int* __restrict__ done_ctr) {
    const int bid = blockIdx.x;
    const int q = bid & 3;
    const int bt = bid >> 2;
    const int b = bt >> 4;
    const int t = bt & 15;
    const int tid = threadIdx.x;
    __shared__ float sh[NROI * 32];
    __shared__ float sal[NROI][36];
    __shared__ float sas[NROI], sad[NROI], sasm[NROI], sasp[NROI];
    __shared__ float red[NROI][8][4];
    __shared__ float red2[8][8][4];

    const int base = b * NODES + t * NROI;
    const float* src = h2 + (size_t)base * D2 + q * 32;
    {
        int row = tid >> 3, c4 = tid & 7;
        *(float4*)&sh[row * 32 + c4 * 4] = *(const float4*)&src[(size_t)row * D2 + c4 * 4];
    }
    if (tid < NROI) {
        sas[tid] = a_s[base + tid];
        sad[tid] = a_d[base + tid];
        sasm[tid] = (t > 0) ? a_s[base - NROI + tid] : 0.0f;
        sasp[tid] = (t < TT - 1) ? a_s[base + NROI + tid] : 0.0f;
    }
    __syncthreads();

    softmax_rows(sas, sad, sasm, sasp, sal, t, tid);
    __syncthreads();

    const float* hprev = h2 + (size_t)(base - NROI) * D2 + q * 32;
    const float* hnext = h2 + (size_t)(base + NROI) * D2 + q * 32;

    {
        const int r = tid >> 3, chq = tid & 7;
        const int ch0 = chq * 4;
        const float4 bb = *(const float4*)&b2[q * 32 + ch0];
        f32x4 acc = (f32x4)0.0f;
#pragma unroll
        for (int sb = 0; sb < NROI; sb += 4) {
            f32x4 a4 = *(const f32x4*)&sal[r][sb];
#pragma unroll
            for (int k = 0; k < 4; ++k) {
                f32x4 v = *(const f32x4*)&sh[(sb + k) * 32 + ch0];
                acc += a4[k] * v;
            }
        }
        if (t > 0) {
            f32x4 v = *(const f32x4*)&hprev[(size_t)r * D2 + ch0];
            acc += sal[r][32] * v;
        }
        if (t < TT - 1) {
            f32x4 v = *(const f32x4*)&hnext[(size_t)r * D2 + ch0];
            acc += sal[r][33] * v;
        }
        acc[0] += bb.x; acc[1] += bb.y; acc[2] += bb.z; acc[3] += bb.w;
#pragma unroll
        for (int k = 0; k < 4; ++k) acc[k] = acc[k] > 0.f ? acc[k] : expf(acc[k]) - 1.f;
        *(f32x4*)&red[r][chq][0] = acc;
    }
    __syncthreads();
    if (tid < 64) {
        const int seg = tid >> 3, cq = tid & 7;
        float4 s = make_float4(0.f, 0.f, 0.f, 0.f);
#pragma unroll
        for (int rr = seg * 4; rr < seg * 4 + 4; ++rr) {
            float4 v = *(const float4*)&red[rr][cq][0];
            s.x += v.x; s.y += v.y; s.z += v.z; s.w += v.w;
        }
        *(float4*)&red2[seg][cq][0] = s;
    }
    __syncthreads();
    if (tid < 8) {
        float4 s = make_float4(0.f, 0.f, 0.f, 0.f);
#pragma unroll
        for (int seg = 0; seg < 8; ++seg) {
            float4 v = *(const float4*)&red2[seg][tid][0];
            s.x += v.x; s.y += v.y; s.z += v.z; s.w += v.w;
        }
        *(float4*)&pg[(size_t)bt * D2 + q * 32 + tid * 4] = s;
    }

    // ---- last-block fused pool + classifier ----
    __threadfence();                         // release pg writes device-wide
    __shared__ int lastFlag;
    if (tid == 0) {
        int prev = atomicAdd(done_ctr, 1);
        lastFlag = (prev == BB * TT * 4 - 1);
    }
    __syncthreads();
    if (!lastFlag) return;
    __threadfence();                         // acquire other blocks' pg writes

    __shared__ float sg[BB][D2 + 4];         // +4 pad: avoid 16-way bank conflict
    for (int i = tid; i < BB * D2; i += 256) {
        int bb2 = i >> 7, c = i & 127;
        float s = 0.0f;
        const volatile float* pgv = (const volatile float*)pg;
#pragma unroll
        for (int t2 = 0; t2 < TT; ++t2)
            s += pgv[(size_t)(bb2 * TT + t2) * D2 + c];
        sg[bb2][c] = s;
    }
    __syncthreads();
    if (tid < 32) {
        const int bo = tid >> 1, j = tid & 1;
        float p = 0.0f;
        for (int c = 0; c < 128; ++c) p += sg[bo][c] * fw[c * 2 + j];
        out[bo * 2 + j] = p * (1.0f / (float)NODES) + fb[j];
    }
}

// ---------------------------------------------------------------------------
extern "C" void kernel_launch(void* const* d_in, const int* in_sizes, int n_in,
                              void* d_out, int out_size, void* d_ws, size_t ws_size,
                              hipStream_t stream) {
    const float* X        = (const float*)d_in[0];   // (16, 512, 768)
    const float* W1       = (const float*)d_in[1];   // (768, 512)
    const float* att_src1 = (const float*)d_in[2];   // (4, 128)
    const float* att_dst1 = (const float*)d_in[3];   // (4, 128)
    const float* b1       = (const float*)d_in[4];   // (512)
    const float* W2       = (const float*)d_in[5];   // (512, 128)
    const float* att_src2 = (const float*)d_in[6];   // (1, 128)
    const float* att_dst2 = (const float*)d_in[7];   // (1, 128)
    const float* b2       = (const float*)d_in[8];   // (128)
    const float* fc_w     = (const float*)d_in[9];   // (128, 768)
    const float* fc_b     = (const float*)d_in[10];  // (768)
    const float* cls_w    = (const float*)d_in[11];  // (768, 2)
    const float* cls_b    = (const float*)d_in[12];  // (2)
    float* out = (float*)d_out;

    float* ws = (float*)d_ws;
    short* h1b = (short*)ws;                        // 8192*512 bf16 = [0, 2M floats)
    float* h2  = ws + 2 * 1024 * 1024;              // fp32 [2M, 3M)
    float* as1 = ws + 3 * 1024 * 1024;              // 8192*4
    float* ad1 = as1 + MROWS * 4;                   // 8192*4
    float* as2 = ad1 + MROWS * 4;                   // 8192
    float* ad2 = as2 + MROWS;                       // 8192
    float* pg  = ad2 + MROWS;                       // 2048
    float* fw  = pg + BB * TT * D2;                 // 256
    float* fb  = fw + 256;                          // 2
    int*   ctr = (int*)(fw + 512);                  // 1
    short* x1b = (short*)(ws + 4 * 1024 * 1024);    // 8192*512 bf16 [4M, 6M)
    short* w1h = (short*)(ws + 6 * 1024 * 1024);    // 512*768
    short* w1l = w1h + D1 * HID;
    short* w2h = w1l + D1 * HID;                    // 128*512
    short* w2l = w2h + D2 * D1;

    // 0) weight prep + counter zero (X conversion fused into gemm1's staging)
    prep_kernel<<<113, 256, 0, stream>>>(W1, w1h, w1l, W2, w2h, w2l,
                                         fc_w, fc_b, cls_w, cls_b, fw, fb, ctr);
    // 1) h1(bf16) = X @ W1 (A = fp32 X, RNE on the fly; W1 split) + proj
    gemm_ps_kernel<4, true, true><<<dim3(D1 / 128, MROWS / 64), 256, 0, stream>>>(
        X, w1h, w1l, h1b, att_src1, att_dst1, as1, ad1, D1, HID);
    // 2) edge agg layer 1 -> x1 (single RNE bf16), per-head blocks
    edge_agg1_kernel<<<BB * TT * 4, 256, 0, stream>>>(h1b, as1, ad1, b1, x1b);
    // 3) h2(fp32) = x1 @ W2 (2-term) with fused layer-2 attention projections
    gemm_ps_kernel<1, false, false><<<dim3(D2 / 128, MROWS / 64), 256, 0, stream>>>(
        x1b, w2h, w2l, h2, att_src2, att_dst2, as2, ad2, D2, D1);
    // 4) edge agg layer 2 + pool partials + (last block) classifier -> out
    edge_agg2_pool_kernel<<<BB * TT * 4, 256, 0, stream>>>(h2, as2, ad2, b2, pg,
                                                           fw, fb, out, ctr);
}

// Round 18
// 89.141 us; speedup vs baseline: 2.1739x; 2.1739x over previous
//
#include <hip/hip_runtime.h>
#include <hip/hip_bf16.h>
#include <math.h>

// Problem constants
#define TT 16
#define NROI 32
#define BB 16
#define HID 768
#define NODES 512            // per graph
#define MROWS (BB * NODES)   // 8192
#define D1 512               // H=4, C=128
#define D2 128               // H=1, C=128

typedef __attribute__((ext_vector_type(8))) short short8;
typedef __attribute__((ext_vector_type(4))) float f32x4;

__device__ __forceinline__ void bf16_split(float v, short& h, short& l) {
    unsigned u = __float_as_uint(v);
    h = (short)(u >> 16);
    float r = v - __uint_as_float(u & 0xFFFF0000u);
    l = (short)(__float_as_uint(r) >> 16);
}

// round-to-nearest-even bf16 (unbiased; errors sqrt-N cancel in long sums)
__device__ __forceinline__ short bf16_rne(float v) {
    unsigned u = __float_as_uint(v);
    unsigned r = u + 0x7FFF + ((u >> 16) & 1);
    return (short)(r >> 16);
}
__device__ __forceinline__ float bf16_f32(short s) {
    return __uint_as_float(((unsigned)(unsigned short)s) << 16);
}

__device__ __forceinline__ float lrelu02(float v) { return v > 0.0f ? v : 0.2f * v; }

// ---------------------------------------------------------------------------
// prep_kernel: W1/W2 transpose+split (112 blocks) + classifier fuse (1 block).
// X conversion is fused into gemm1's A-staging (no X round-trip).
// ---------------------------------------------------------------------------
__launch_bounds__(256)
__global__ void prep_kernel(const float* __restrict__ W1, short* __restrict__ w1h,
                            short* __restrict__ w1l, const float* __restrict__ W2,
                            short* __restrict__ w2h, short* __restrict__ w2l,
                            const float* __restrict__ fc_w, const float* __restrict__ fc_b,
                            const float* __restrict__ cls_w, const float* __restrict__ cls_b,
                            float* __restrict__ fw, float* __restrict__ fb) {
    const int bid = blockIdx.x;
    const int tid = threadIdx.x;

    if (bid < 112) {
        __shared__ unsigned tile[64][65];
        const float* W; short *hi, *lo; int K, N, k0, n0;
        if (bid < 96) {
            W = W1; hi = w1h; lo = w1l; K = HID; N = D1;
            k0 = (bid >> 3) * 64; n0 = (bid & 7) * 64;
        } else {
            int idx = bid - 96;
            W = W2; hi = w2h; lo = w2l; K = D1; N = D2;
            k0 = (idx >> 1) * 64; n0 = (idx & 1) * 64;
        }
#pragma unroll
        for (int it = 0; it < 16; ++it) {
            int i = it * 256 + tid;
            int r = i >> 6, j = i & 63;
            float v = W[(size_t)(k0 + r) * N + n0 + j];
            short h, l;
            bf16_split(v, h, l);
            tile[r][j] = ((unsigned)(unsigned short)h << 16) | (unsigned)(unsigned short)l;
        }
        __syncthreads();
#pragma unroll
        for (int it = 0; it < 16; ++it) {
            int i = it * 256 + tid;
            int rr = i >> 6, c = i & 63;
            unsigned p = tile[c][rr];
            hi[(size_t)(n0 + rr) * K + k0 + c] = (short)(p >> 16);
            lo[(size_t)(n0 + rr) * K + k0 + c] = (short)(p & 0xFFFF);
        }
        return;
    }

    // ---- fuse_cls ----
    const int t = tid;
    const int c = t >> 1, j = t & 1;
    const float* wr = fc_w + (size_t)c * HID;
    float s = 0.0f;
#pragma unroll 4
    for (int o = 0; o < HID; o += 4) {
        float4 w4 = *(const float4*)(wr + o);
        s += w4.x * cls_w[(o + 0) * 2 + j] + w4.y * cls_w[(o + 1) * 2 + j]
           + w4.z * cls_w[(o + 2) * 2 + j] + w4.w * cls_w[(o + 3) * 2 + j];
    }
    fw[c * 2 + j] = s;

    __shared__ float p0[256], p1[256];
    float a0 = 0.0f, a1 = 0.0f;
    for (int o = t * 3; o < t * 3 + 3; ++o) {
        float v = fc_b[o];
        a0 += v * cls_w[o * 2 + 0];
        a1 += v * cls_w[o * 2 + 1];
    }
    p0[t] = a0; p1[t] = a1;
    __syncthreads();
    for (int off = 128; off > 0; off >>= 1) {
        if (t < off) { p0[t] += p0[t + off]; p1[t] += p1[t + off]; }
        __syncthreads();
    }
    if (t == 0) { fb[0] = p0[0] + cls_b[0]; fb[1] = p1[0] + cls_b[1]; }
}

// ---------------------------------------------------------------------------
// bf16 MFMA GEMM, 2-term (A single bf16; B split hi/lo).
// AFP32: A source is fp32, RNE-converted in-register during staging.
// CBF16: C stored as RNE bf16 (short*), else fp32.
// PROJ=4: layer-1 head projections (head = blockIdx.x); PROJ=1: layer-2.
// ---------------------------------------------------------------------------
template <int PROJ, bool AFP32, bool CBF16>
__launch_bounds__(256)
__global__ void gemm_ps_kernel(const void* __restrict__ Av,
                               const short* __restrict__ Bh, const short* __restrict__ Bl,
                               void* __restrict__ Cv,
                               const float* __restrict__ asw, const float* __restrict__ adw,
                               float* __restrict__ as_o, float* __restrict__ ad_o,
                               int N, int K) {
    constexpr int BM = 64, BN = 128, BK = 32, LD = BK + 8;
    __shared__ __align__(16) short As[2][BM][LD];
    __shared__ __align__(16) short Bs[2][2][BN][LD];
    __shared__ float eps[2][BM], epd[2][BM];

    const int tid = threadIdx.x, lane = tid & 63, wid = tid >> 6;
    const int brow = blockIdx.y * BM, bcol = blockIdx.x * BN;
    const int wm = (wid >> 1) * 32, wn = (wid & 1) * 64;
    const int frow = lane & 15, fk = (lane >> 4) * 8;

    f32x4 acc[2][4];
#pragma unroll
    for (int m = 0; m < 2; ++m)
#pragma unroll
        for (int n = 0; n < 4; ++n) acc[m][n] = (f32x4)0.0f;

    short8 a_h, b_h[2], b_l[2];
    const int arow = tid >> 2, ag = tid & 3;

    auto load_tiles = [&](int k0) {
        const size_t aoff = (size_t)(brow + arow) * K + k0 + ag * 8;
        if constexpr (AFP32) {
            const float* Af = (const float*)Av;
            float4 v0 = *(const float4*)(Af + aoff);
            float4 v1 = *(const float4*)(Af + aoff + 4);
            a_h[0] = bf16_rne(v0.x); a_h[1] = bf16_rne(v0.y);
            a_h[2] = bf16_rne(v0.z); a_h[3] = bf16_rne(v0.w);
            a_h[4] = bf16_rne(v1.x); a_h[5] = bf16_rne(v1.y);
            a_h[6] = bf16_rne(v1.z); a_h[7] = bf16_rne(v1.w);
        } else {
            a_h = *(const short8*)((const short*)Av + aoff);
        }
#pragma unroll
        for (int it = 0; it < 2; ++it) {
            int idx = it * 256 + tid;
            int row = idx >> 2, g = idx & 3;
            const size_t boff = (size_t)(bcol + row) * K + k0 + g * 8;
            b_h[it] = *(const short8*)(Bh + boff);
            b_l[it] = *(const short8*)(Bl + boff);
        }
    };
    auto write_tiles = [&](int buf) {
        *(short8*)&As[buf][arow][ag * 8] = a_h;
#pragma unroll
        for (int it = 0; it < 2; ++it) {
            int idx = it * 256 + tid;
            int row = idx >> 2, g = idx & 3;
            *(short8*)&Bs[buf][0][row][g * 8] = b_h[it];
            *(short8*)&Bs[buf][1][row][g * 8] = b_l[it];
        }
    };

    const int NT = K / BK;
    load_tiles(0);
    write_tiles(0);
    __syncthreads();
    int cur = 0;
    for (int t = 0; t < NT; ++t) {
        if (t + 1 < NT) load_tiles((t + 1) * BK);

        short8 ah[2], bhf[4], blf[4];
#pragma unroll
        for (int m = 0; m < 2; ++m)
            ah[m] = *(const short8*)&As[cur][wm + m * 16 + frow][fk];
#pragma unroll
        for (int n = 0; n < 4; ++n) {
            bhf[n] = *(const short8*)&Bs[cur][0][wn + n * 16 + frow][fk];
            blf[n] = *(const short8*)&Bs[cur][1][wn + n * 16 + frow][fk];
        }
#pragma unroll
        for (int m = 0; m < 2; ++m)
#pragma unroll
            for (int n = 0; n < 4; ++n) {
                acc[m][n] = __builtin_amdgcn_mfma_f32_16x16x32_bf16(ah[m], bhf[n], acc[m][n], 0, 0, 0);
                acc[m][n] = __builtin_amdgcn_mfma_f32_16x16x32_bf16(ah[m], blf[n], acc[m][n], 0, 0, 0);
            }

        if (t + 1 < NT) write_tiles(cur ^ 1);
        __syncthreads();
        cur ^= 1;
    }

    // C write: D[row=(lane>>4)*4+j][col=lane&15]
#pragma unroll
    for (int m = 0; m < 2; ++m)
#pragma unroll
        for (int n = 0; n < 4; ++n) {
            const int col = bcol + wn + n * 16 + (lane & 15);
            const int r0 = brow + wm + m * 16 + (lane >> 4) * 4;
#pragma unroll
            for (int j = 0; j < 4; ++j) {
                if constexpr (CBF16)
                    ((short*)Cv)[(size_t)(r0 + j) * N + col] = bf16_rne(acc[m][n][j]);
                else
                    ((float*)Cv)[(size_t)(r0 + j) * N + col] = acc[m][n][j];
            }
        }

    if constexpr (PROJ > 0) {
        const int hh = (PROJ == 4) ? (int)blockIdx.x : 0;
        float aw[4], dw[4];
#pragma unroll
        for (int n = 0; n < 4; ++n) {
            int c = wn + n * 16 + (lane & 15);
            aw[n] = asw[hh * 128 + c];
            dw[n] = adw[hh * 128 + c];
        }
        float ps[2][4], pd[2][4];
#pragma unroll
        for (int m = 0; m < 2; ++m)
#pragma unroll
            for (int j = 0; j < 4; ++j) {
                float s = 0.0f, d = 0.0f;
#pragma unroll
                for (int n = 0; n < 4; ++n) {
                    s += acc[m][n][j] * aw[n];
                    d += acc[m][n][j] * dw[n];
                }
                ps[m][j] = s; pd[m][j] = d;
            }
#pragma unroll
        for (int off = 1; off < 16; off <<= 1)
#pragma unroll
            for (int m = 0; m < 2; ++m)
#pragma unroll
                for (int j = 0; j < 4; ++j) {
                    ps[m][j] += __shfl_xor(ps[m][j], off);
                    pd[m][j] += __shfl_xor(pd[m][j], off);
                }
        if ((lane & 15) == 0) {
#pragma unroll
            for (int m = 0; m < 2; ++m)
#pragma unroll
                for (int j = 0; j < 4; ++j) {
                    int rl = wm + m * 16 + (lane >> 4) * 4 + j;
                    eps[wid & 1][rl] = ps[m][j];
                    epd[wid & 1][rl] = pd[m][j];
                }
        }
        __syncthreads();
        if (tid < BM) {
            float s = eps[0][tid] + eps[1][tid];
            float d = epd[0][tid] + epd[1][tid];
            if (PROJ == 4) {
                as_o[(size_t)(brow + tid) * 4 + hh] = s;
                ad_o[(size_t)(brow + tid) * 4 + hh] = d;
            } else {
                as_o[brow + tid] = s;
                ad_o[brow + tid] = d;
            }
        }
    }
}

// ---------------------------------------------------------------------------
// Wave-parallel per-row softmax into sal[NROI][36].
// ---------------------------------------------------------------------------
__device__ __forceinline__ void softmax_rows(const float* sas, const float* sad,
                                             const float* sasm, const float* sasp,
                                             float (*sal)[36], int t, int tid) {
    if (tid < 128) {
        const int r = tid >> 2, p = tid & 3;
        const float ad = sad[r];
        float e[8];
        float m = -1e30f;
#pragma unroll
        for (int k = 0; k < 8; ++k) {
            e[k] = lrelu02(sas[p * 8 + k] + ad);
            m = fmaxf(m, e[k]);
        }
        m = fmaxf(m, __shfl_xor(m, 1));
        m = fmaxf(m, __shfl_xor(m, 2));
        const bool hp = (t > 0), hn = (t < TT - 1);
        float vp = 0.0f, vn = 0.0f;
        if (hp) { vp = lrelu02(sasm[r] + ad); m = fmaxf(m, vp); }
        if (hn) { vn = lrelu02(sasp[r] + ad); m = fmaxf(m, vn); }
        float sum = 0.0f;
#pragma unroll
        for (int k = 0; k < 8; ++k) {
            float x = expf(e[k] - m);
            e[k] = x;
            sum += x;
        }
        sum += __shfl_xor(sum, 1);
        sum += __shfl_xor(sum, 2);
        float ep = hp ? expf(vp - m) : 0.0f;
        float en = hn ? expf(vn - m) : 0.0f;
        sum += ep + en;
        float inv = 1.0f / (sum + 1e-16f);
#pragma unroll
        for (int k = 0; k < 8; ++k) sal[r][p * 8 + k] = e[k] * inv;
        if (p == 0) { sal[r][32] = ep * inv; sal[r][33] = en * inv; }
    }
}

// ---------------------------------------------------------------------------
// GAT layer-1 edge agg, per-head blocks, register-blocked, bf16 h1 input,
// single-RNE-bf16 x1 output.
// ---------------------------------------------------------------------------
__launch_bounds__(256)
__global__ void edge_agg1_kernel(const short* __restrict__ h1b, const float* __restrict__ a_s,
                                 const float* __restrict__ a_d, const float* __restrict__ b1,
                                 short* __restrict__ x1b) {
    const int bid = blockIdx.x;
    const int hh = bid & 3;
    const int bt = bid >> 2;
    const int b = bt >> 4;
    const int t = bt & 15;
    const int tid = threadIdx.x;
    __shared__ float sh[NROI * 128];     // 16 KB (fp32, converted at stage)
    __shared__ float sal[NROI][36];
    __shared__ float sas[NROI], sad[NROI], sasm[NROI], sasp[NROI];

    const int base = b * NODES + t * NROI;
    const short* src = h1b + (size_t)base * D1 + hh * 128;
#pragma unroll
    for (int it = 0; it < 2; ++it) {
        int i = it * 256 + tid;
        int row = i >> 4, c8 = (i & 15) * 8;
        short8 v = *(const short8*)&src[(size_t)row * D1 + c8];
        float* dst = &sh[row * 128 + c8];
#pragma unroll
        for (int j = 0; j < 8; ++j) dst[j] = bf16_f32(v[j]);
    }
    if (tid < NROI) {
        sas[tid] = a_s[(base + tid) * 4 + hh];
        sad[tid] = a_d[(base + tid) * 4 + hh];
        sasm[tid] = (t > 0) ? a_s[(base - NROI + tid) * 4 + hh] : 0.0f;
        sasp[tid] = (t < TT - 1) ? a_s[(base + NROI + tid) * 4 + hh] : 0.0f;
    }
    __syncthreads();

    softmax_rows(sas, sad, sasm, sasp, sal, t, tid);
    __syncthreads();

    const short* hprev = h1b + (size_t)(base - NROI) * D1 + hh * 128;
    const short* hnext = h1b + (size_t)(base + NROI) * D1 + hh * 128;
    short* outp = x1b + (size_t)base * D1 + hh * 128;

    const int g = tid >> 5;              // row group 0..7
    const int ch0 = (tid & 31) * 4;      // channel within slice
    const float4 bb = *(const float4*)&b1[hh * 128 + ch0];

    f32x4 acc[4];
#pragma unroll
    for (int rr = 0; rr < 4; ++rr) acc[rr] = (f32x4)0.0f;

#pragma unroll
    for (int sb = 0; sb < NROI; sb += 4) {
        f32x4 a0 = *(const f32x4*)&sal[g][sb];
        f32x4 a1 = *(const f32x4*)&sal[g + 8][sb];
        f32x4 a2 = *(const f32x4*)&sal[g + 16][sb];
        f32x4 a3 = *(const f32x4*)&sal[g + 24][sb];
#pragma unroll
        for (int k = 0; k < 4; ++k) {
            f32x4 v = *(const f32x4*)&sh[(sb + k) * 128 + ch0];
            acc[0] += a0[k] * v;
            acc[1] += a1[k] * v;
            acc[2] += a2[k] * v;
            acc[3] += a3[k] * v;
        }
    }

#pragma unroll
    for (int rr = 0; rr < 4; ++rr) {
        const int r = g + rr * 8;
        f32x4 a = acc[rr];
        if (t > 0) {
            short4 v4 = *(const short4*)&hprev[(size_t)r * D1 + ch0];
            float w = sal[r][32];
            a[0] += w * bf16_f32(v4.x); a[1] += w * bf16_f32(v4.y);
            a[2] += w * bf16_f32(v4.z); a[3] += w * bf16_f32(v4.w);
        }
        if (t < TT - 1) {
            short4 v4 = *(const short4*)&hnext[(size_t)r * D1 + ch0];
            float w = sal[r][33];
            a[0] += w * bf16_f32(v4.x); a[1] += w * bf16_f32(v4.y);
            a[2] += w * bf16_f32(v4.z); a[3] += w * bf16_f32(v4.w);
        }
        a[0] += bb.x; a[1] += bb.y; a[2] += bb.z; a[3] += bb.w;
#pragma unroll
        for (int k = 0; k < 4; ++k) a[k] = a[k] > 0.f ? a[k] : expf(a[k]) - 1.f;
        short4 o;
        o.x = bf16_rne(a[0]); o.y = bf16_rne(a[1]);
        o.z = bf16_rne(a[2]); o.w = bf16_rne(a[3]);
        *(short4*)&outp[(size_t)r * D1 + ch0] = o;
    }
}

// ---------------------------------------------------------------------------
// GAT layer-2 edge agg + pool partials, per-quarter blocks.
// ---------------------------------------------------------------------------
__launch_bounds__(256)
__global__ void edge_agg2_pool_kernel(const float* __restrict__ h2, const float* __restrict__ a_s,
                                      const float* __restrict__ a_d, const float* __restrict__ b2,
                                      float* __restrict__ pg) {
    const int bid = blockIdx.x;
    const int q = bid & 3;
    const int bt = bid >> 2;
    const int b = bt >> 4;
    const int t = bt & 15;
    const int tid = threadIdx.x;
    __shared__ float sh[NROI * 32];
    __shared__ float sal[NROI][36];
    __shared__ float sas[NROI], sad[NROI], sasm[NROI], sasp[NROI];
    __shared__ float red[NROI][8][4];
    __shared__ float red2[8][8][4];

    const int base = b * NODES + t * NROI;
    const float* src = h2 + (size_t)base * D2 + q * 32;
    {
        int row = tid >> 3, c4 = tid & 7;
        *(float4*)&sh[row * 32 + c4 * 4] = *(const float4*)&src[(size_t)row * D2 + c4 * 4];
    }
    if (tid < NROI) {
        sas[tid] = a_s[base + tid];
        sad[tid] = a_d[base + tid];
        sasm[tid] = (t > 0) ? a_s[base - NROI + tid] : 0.0f;
        sasp[tid] = (t < TT - 1) ? a_s[base + NROI + tid] : 0.0f;
    }
    __syncthreads();

    softmax_rows(sas, sad, sasm, sasp, sal, t, tid);
    __syncthreads();

    const float* hprev = h2 + (size_t)(base - NROI) * D2 + q * 32;
    const float* hnext = h2 + (size_t)(base + NROI) * D2 + q * 32;

    {
        const int r = tid >> 3, chq = tid & 7;
        const int ch0 = chq * 4;
        const float4 bb = *(const float4*)&b2[q * 32 + ch0];
        f32x4 acc = (f32x4)0.0f;
#pragma unroll
        for (int sb = 0; sb < NROI; sb += 4) {
            f32x4 a4 = *(const f32x4*)&sal[r][sb];
#pragma unroll
            for (int k = 0; k < 4; ++k) {
                f32x4 v = *(const f32x4*)&sh[(sb + k) * 32 + ch0];
                acc += a4[k] * v;
            }
        }
        if (t > 0) {
            f32x4 v = *(const f32x4*)&hprev[(size_t)r * D2 + ch0];
            acc += sal[r][32] * v;
        }
        if (t < TT - 1) {
            f32x4 v = *(const f32x4*)&hnext[(size_t)r * D2 + ch0];
            acc += sal[r][33] * v;
        }
        acc[0] += bb.x; acc[1] += bb.y; acc[2] += bb.z; acc[3] += bb.w;
#pragma unroll
        for (int k = 0; k < 4; ++k) acc[k] = acc[k] > 0.f ? acc[k] : expf(acc[k]) - 1.f;
        *(f32x4*)&red[r][chq][0] = acc;
    }
    __syncthreads();
    if (tid < 64) {
        const int seg = tid >> 3, cq = tid & 7;
        float4 s = make_float4(0.f, 0.f, 0.f, 0.f);
#pragma unroll
        for (int rr = seg * 4; rr < seg * 4 + 4; ++rr) {
            float4 v = *(const float4*)&red[rr][cq][0];
            s.x += v.x; s.y += v.y; s.z += v.z; s.w += v.w;
        }
        *(float4*)&red2[seg][cq][0] = s;
    }
    __syncthreads();
    if (tid < 8) {
        float4 s = make_float4(0.f, 0.f, 0.f, 0.f);
#pragma unroll
        for (int seg = 0; seg < 8; ++seg) {
            float4 v = *(const float4*)&red2[seg][tid][0];
            s.x += v.x; s.y += v.y; s.z += v.z; s.w += v.w;
        }
        *(float4*)&pg[(size_t)bt * D2 + q * 32 + tid * 4] = s;
    }
}

// ---------------------------------------------------------------------------
// Final: sum pg over frames, apply collapsed classifier. 16 blocks x 128 thr.
// ---------------------------------------------------------------------------
__launch_bounds__(128)
__global__ void pool_cls_kernel(const float* __restrict__ pg, const float* __restrict__ fw,
                                const float* __restrict__ fb, float* __restrict__ out) {
    const int b = blockIdx.x;
    const int tid = threadIdx.x;
    __shared__ float sg[D2];
    float s = 0.0f;
#pragma unroll
    for (int t = 0; t < TT; ++t) s += pg[(size_t)(b * TT + t) * D2 + tid];
    sg[tid] = s;
    __syncthreads();
    const int lane = tid & 63, w = tid >> 6;
    float p = sg[lane] * fw[lane * 2 + w] + sg[lane + 64] * fw[(lane + 64) * 2 + w];
#pragma unroll
    for (int off = 32; off > 0; off >>= 1) p += __shfl_down(p, off);
    if (lane == 0) out[b * 2 + w] = p * (1.0f / (float)NODES) + fb[w];
}

// ---------------------------------------------------------------------------
extern "C" void kernel_launch(void* const* d_in, const int* in_sizes, int n_in,
                              void* d_out, int out_size, void* d_ws, size_t ws_size,
                              hipStream_t stream) {
    const float* X        = (const float*)d_in[0];   // (16, 512, 768)
    const float* W1       = (const float*)d_in[1];   // (768, 512)
    const float* att_src1 = (const float*)d_in[2];   // (4, 128)
    const float* att_dst1 = (const float*)d_in[3];   // (4, 128)
    const float* b1       = (const float*)d_in[4];   // (512)
    const float* W2       = (const float*)d_in[5];   // (512, 128)
    const float* att_src2 = (const float*)d_in[6];   // (1, 128)
    const float* att_dst2 = (const float*)d_in[7];   // (1, 128)
    const float* b2       = (const float*)d_in[8];   // (128)
    const float* fc_w     = (const float*)d_in[9];   // (128, 768)
    const float* fc_b     = (const float*)d_in[10];  // (768)
    const float* cls_w    = (const float*)d_in[11];  // (768, 2)
    const float* cls_b    = (const float*)d_in[12];  // (2)
    float* out = (float*)d_out;

    float* ws = (float*)d_ws;
    short* h1b = (short*)ws;                        // 8192*512 bf16 = [0, 2M floats)
    float* h2  = ws + 2 * 1024 * 1024;              // fp32 [2M, 3M)
    float* as1 = ws + 3 * 1024 * 1024;              // 8192*4
    float* ad1 = as1 + MROWS * 4;                   // 8192*4
    float* as2 = ad1 + MROWS * 4;                   // 8192
    float* ad2 = as2 + MROWS;                       // 8192
    float* pg  = ad2 + MROWS;                       // 2048
    float* fw  = pg + BB * TT * D2;                 // 256
    float* fb  = fw + 256;                          // 2
    short* x1b = (short*)(ws + 4 * 1024 * 1024);    // 8192*512 bf16 [4M, 6M)
    short* w1h = (short*)(ws + 6 * 1024 * 1024);    // 512*768
    short* w1l = w1h + D1 * HID;
    short* w2h = w1l + D1 * HID;                    // 128*512
    short* w2l = w2h + D2 * D1;

    // 0) weight prep only (X conversion fused into gemm1's staging)
    prep_kernel<<<113, 256, 0, stream>>>(W1, w1h, w1l, W2, w2h, w2l,
                                         fc_w, fc_b, cls_w, cls_b, fw, fb);
    // 1) h1(bf16) = X @ W1 (A = fp32 X, RNE on the fly; W1 split) + proj
    gemm_ps_kernel<4, true, true><<<dim3(D1 / 128, MROWS / 64), 256, 0, stream>>>(
        X, w1h, w1l, h1b, att_src1, att_dst1, as1, ad1, D1, HID);
    // 2) edge agg layer 1 -> x1 (single RNE bf16), per-head blocks
    edge_agg1_kernel<<<BB * TT * 4, 256, 0, stream>>>(h1b, as1, ad1, b1, x1b);
    // 3) h2(fp32) = x1 @ W2 (2-term) with fused layer-2 attention projections
    gemm_ps_kernel<1, false, false><<<dim3(D2 / 128, MROWS / 64), 256, 0, stream>>>(
        x1b, w2h, w2l, h2, att_src2, att_dst2, as2, ad2, D2, D1);
    // 4) edge agg layer 2 + pool partials -> pg
    edge_agg2_pool_kernel<<<BB * TT * 4, 256, 0, stream>>>(h2, as2, ad2, b2, pg);
    // 5) frame-sum + collapsed fc/classifier
    pool_cls_kernel<<<BB, 128, 0, stream>>>(pg, fw, fb, out);
}